// Round 3
// baseline (448.898 us; speedup 1.0000x reference)
//
#include <hip/hip_runtime.h>
#include <math.h>

#define BB 4096
#define LL 200
#define HH 32
#define PF 8      // prefetch depth (outstanding global loads per wave)

// ---------------------------------------------------------------------------
// R6: phase A byte-identical to R3 (best measured: 143.5 us total).
// Phase B rewritten: the old MLP staged weight rows per-THREAD
// (global_load_dwordx4 with 64 lanes striding 1 KB = 64 cache lines per
// instruction, ~1M such gathers per grid). Theory: that TA-bound gather,
// not the local_states stream, is the bulk of the dispatch  (R3/R4/R5
// varied stream path+occupancy 3-8x, time barely moved; R4's scratch
// spill proven by WRITE_SIZE=67.6MB=threads*128B).
// New phase B: wave owns 64 units; 16 k-lanes read each weight row as
// contiguous float4 (coalesced), dot vs LDS-hoisted activations, reduce
// via shfl_xor 1/2/4/8 (DPP), row-group lane 0 writes. No w[64] array.
// ---------------------------------------------------------------------------

__global__ __launch_bounds__(256) void actor_fused_kernel(
    const float* __restrict__ gs,
    const float* __restrict__ ls,
    const float* __restrict__ W_w, const float* __restrict__ W_b,
    const float* __restrict__ U_w, const float* __restrict__ U_b,
    const float* __restrict__ att_w, const float* __restrict__ att_b,
    const float* __restrict__ l1_w, const float* __restrict__ l1_b,
    const float* __restrict__ l2_w, const float* __restrict__ l2_b,
    const float* __restrict__ l3_w, const float* __restrict__ l3_b,
    float* __restrict__ out)
{
    __shared__ float c_lds[4 * 64];
    __shared__ float y_lds[4 * 64];
    __shared__ __align__(16) float s_x [4 * 64];
    __shared__ __align__(16) float s_a1[4 * 256];
    __shared__ __align__(16) float s_a2[4 * 260];  // pad 260: float4-able

    const int tid  = threadIdx.x;
    const int lane = tid & 63;
    const int wid  = tid >> 6;
    const int b    = blockIdx.x * 4 + wid;

    const int h    = lane & 31;   // owned hidden unit (both halves)
    const int half = lane >> 5;   // d-half for 64-d dots
    const int q    = lane & 15;   // d-quad within l-group
    const int lg   = lane >> 4;   // l-group 0..3

    // ================= Phase A: attention pooling (per wave) =================
    // (byte-identical to R3's best-measured version)

    const float4* g4 = (const float4*)(gs + (size_t)b * 64);
    const float4* W4 = (const float4*)(W_w);
    float wg = (half == 0) ? W_b[h] : 0.f;
    #pragma unroll
    for (int dd = 0; dd < 8; ++dd) {
        float4 gv = g4[half * 8 + dd];
        float4 wv = W4[h * 16 + half * 8 + dd];
        wg += gv.x * wv.x + gv.y * wv.y + gv.z * wv.z + gv.w * wv.w;
    }
    wg += __shfl_xor(wg, 32);     // all lanes now hold wg[h]

    float gt = wg * att_w[h];
    float t2 = wg * att_w[HH + h];
    #pragma unroll
    for (int m = 1; m < 32; m <<= 1) {
        gt += __shfl_xor(gt, m);
        t2 += __shfl_xor(t2, m);
    }
    const float attb = att_b[0];
    const float lin0 = gt + t2 + attb;
    const float s0   = (lin0 > 0.f) ? lin0 : 0.01f * lin0;

    float c = 0.f;
    float ubal = 0.f;
    #pragma unroll
    for (int hh = 0; hh < HH; ++hh) {
        const float alh = att_w[HH + hh];        // uniform -> s_load
        c    += alh * U_w[hh * 64 + lane];       // coalesced, L1-hot
        ubal += alh * U_b[hh];
    }
    c_lds[wid * 64 + lane] = c;
    __syncthreads();
    const float4 cq = *(const float4*)&c_lds[wid * 64 + 4 * q];
    const float base = gt + ubal + attb;

    const float4* xs = (const float4*)(ls + (size_t)b * (LL * 64));
    const int idx0 = lg * 16 + q;
    float4 yx = make_float4(0.f, 0.f, 0.f, 0.f);
    float Sacc = 0.f;

    float4 Xbuf[PF];
    #pragma unroll
    for (int i = 0; i < PF; ++i)
        Xbuf[i] = xs[idx0 + i * 64];

    #pragma unroll                 // FULL unroll: ring index compile-time
    for (int t = 0; t < 50; ++t) {
        float4 X = Xbuf[t & (PF - 1)];
        int tn = t + PF;
        if (tn > 49) tn = 49;      // clamped redundant tail (L1-hot)
        Xbuf[t & (PF - 1)] = xs[idx0 + tn * 64];

        float p = X.x * cq.x + X.y * cq.y + X.z * cq.z + X.w * cq.w;
        p += __shfl_xor(p, 1);
        p += __shfl_xor(p, 2);
        p += __shfl_xor(p, 4);
        p += __shfl_xor(p, 8);     // 16-lane group dot: x[l].c
        const float linv = p + base;
        const float sl = (linv > 0.f) ? linv : 0.01f * linv;
        yx.x += sl * X.x;
        yx.y += sl * X.y;
        yx.z += sl * X.z;
        yx.w += sl * X.w;
        Sacc += sl;                // identical across the 16-lane group
    }

    #pragma unroll
    for (int m = 16; m < 64; m <<= 1) {
        yx.x += __shfl_xor(yx.x, m);
        yx.y += __shfl_xor(yx.y, m);
        yx.z += __shfl_xor(yx.z, m);
        yx.w += __shfl_xor(yx.w, m);
        Sacc += __shfl_xor(Sacc, m);
    }
    if (lane < 16) *(float4*)&y_lds[wid * 64 + 4 * q] = yx;
    __syncthreads();

    float V = (half == 0) ? (U_b[h] * Sacc) : 0.f;
    const float4* U4 = (const float4*)U_w;
    const float4* y4 = (const float4*)&y_lds[wid * 64];
    #pragma unroll
    for (int dd = 0; dd < 8; ++dd) {
        float4 uv = U4[h * 16 + half * 8 + dd];
        float4 yv = y4[half * 8 + dd];
        V += uv.x * yv.x + uv.y * yv.y + uv.z * yv.z + uv.w * yv.w;
    }
    V += __shfl_xor(V, 32);        // all lanes hold full V[h]

    const float total = s0 + Sacc;
    const float n0    = s0 / total;
    const float outv  = (lane < 32) ? (n0 * wg) : (V / total);
    s_x[wid * 64 + lane] = fmaxf(outv, 0.f);   // states -> LDS
    __syncthreads();

    // ================= Phase B: MLP 64->256->256->8 (coalesced) ==============
    // Wave wid owns output units [wid*64, wid*64+64). Lane layout:
    //   rg = lane>>4  : batch row 0..3 this lane reduces for
    //   kl = lane&15  : k-slice (16 lanes x float4 cover 64 k's)
    const int rg = lane >> 4;
    const int kl = lane & 15;
    const int u0 = wid * 64;

    // ---- layer 1: k = 64 (one float4 per lane) ----
    {
        const float4 xv = *(const float4*)(s_x + rg * 64 + kl * 4);
        #pragma unroll 8
        for (int i = 0; i < 64; ++i) {
            const int u = u0 + i;
            const float4 wv = *(const float4*)(l1_w + u * 64 + kl * 4);
            float acc = wv.x * xv.x + wv.y * xv.y + wv.z * xv.z + wv.w * xv.w;
            acc += __shfl_xor(acc, 1);
            acc += __shfl_xor(acc, 2);
            acc += __shfl_xor(acc, 4);
            acc += __shfl_xor(acc, 8);   // reduce over the 16 k-lanes
            if (kl == 0)
                s_a1[rg * 256 + u] = fmaxf(acc + l1_b[u], 0.f);
        }
    }
    __syncthreads();

    // ---- layer 2: k = 256 (4 float4 segments per lane) ----
    {
        const float4 av0 = *(const float4*)(s_a1 + rg * 256 +   0 + kl * 4);
        const float4 av1 = *(const float4*)(s_a1 + rg * 256 +  64 + kl * 4);
        const float4 av2 = *(const float4*)(s_a1 + rg * 256 + 128 + kl * 4);
        const float4 av3 = *(const float4*)(s_a1 + rg * 256 + 192 + kl * 4);
        #pragma unroll 4
        for (int i = 0; i < 64; ++i) {
            const int u = u0 + i;
            const float4* wr = (const float4*)(l2_w + (size_t)u * 256);
            const float4 w0v = wr[     kl];
            const float4 w1v = wr[16 + kl];
            const float4 w2v = wr[32 + kl];
            const float4 w3v = wr[48 + kl];
            float acc = w0v.x * av0.x + w0v.y * av0.y + w0v.z * av0.z + w0v.w * av0.w;
            acc      += w1v.x * av1.x + w1v.y * av1.y + w1v.z * av1.z + w1v.w * av1.w;
            acc      += w2v.x * av2.x + w2v.y * av2.y + w2v.z * av2.z + w2v.w * av2.w;
            acc      += w3v.x * av3.x + w3v.y * av3.y + w3v.z * av3.z + w3v.w * av3.w;
            acc += __shfl_xor(acc, 1);
            acc += __shfl_xor(acc, 2);
            acc += __shfl_xor(acc, 4);
            acc += __shfl_xor(acc, 8);   // reduce over the 16 k-lanes
            if (kl == 0)
                s_a2[rg * 260 + u] = fmaxf(acc + l2_b[u], 0.f);
        }
    }
    __syncthreads();

    // ---- layer 3 + sigmoid: threads 0..31, float4 LDS reads (8 KB, tiny) ----
    if (tid < 32) {
        int r = tid >> 3, o = tid & 7;
        float acc = l3_b[o];
        const float4* wr4 = (const float4*)(l3_w + o * 256);
        const float4* a4  = (const float4*)&s_a2[r * 260];
        #pragma unroll 8
        for (int k = 0; k < 64; ++k) {
            float4 av = a4[k];
            float4 wv = wr4[k];
            acc += av.x * wv.x + av.y * wv.y + av.z * wv.z + av.w * wv.w;
        }
        out[(size_t)(blockIdx.x * 4 + r) * 8 + o] =
            1.f / (1.f + __expf(-acc));   // MAX_ACTION = 1
    }
}

// ---------------------------------------------------------------------------
extern "C" void kernel_launch(void* const* d_in, const int* in_sizes, int n_in,
                              void* d_out, int out_size, void* d_ws, size_t ws_size,
                              hipStream_t stream)
{
    const float* gs    = (const float*)d_in[0];
    const float* ls    = (const float*)d_in[1];
    const float* W_w   = (const float*)d_in[2];
    const float* W_b   = (const float*)d_in[3];
    const float* U_w   = (const float*)d_in[4];
    const float* U_b   = (const float*)d_in[5];
    const float* att_w = (const float*)d_in[6];
    const float* att_b = (const float*)d_in[7];
    const float* l1_w  = (const float*)d_in[8];
    const float* l1_b  = (const float*)d_in[9];
    const float* l2_w  = (const float*)d_in[10];
    const float* l2_b  = (const float*)d_in[11];
    const float* l3_w  = (const float*)d_in[12];
    const float* l3_b  = (const float*)d_in[13];

    actor_fused_kernel<<<BB / 4, 256, 0, stream>>>(
        gs, ls, W_w, W_b, U_w, U_b, att_w, att_b,
        l1_w, l1_b, l2_w, l2_b, l3_w, l3_b, (float*)d_out);
}

// Round 4
// 401.130 us; speedup vs baseline: 1.1191x; 1.1191x over previous
//
#include <hip/hip_runtime.h>
#include <math.h>

#define BB 4096
#define LL 200
#define HH 32
#define PF 8       // prefetch depth (outstanding global loads per wave)
#define ROWS 16    // batch rows per block (one per wave)

// ---------------------------------------------------------------------------
// R7: phase A per-wave byte-identical to R3 (best measured). Structural
// change: 16 rows/block (1024 thr, grid 256, ~1 block/CU) so phase B's
// weight traffic is amortized over 16 rows instead of 4.
// R6 post-mortem: swapping phase B alone moved total +83 us => phase B is
// a major cost (R3 ~ 60-70 us phase A + ~75-80 us phase B). Phase B is
// execution-bound garbage (per-thread weight gathers = 64 cache lines per
// instr, re-issued by every 4-row block). Fix: thread owns unit, weight
// chunk in VGPRs, 16-row reuse, LDS-broadcast activations (wave-uniform
// addr = conflict-free), s_a1/s_a2 padded to 260 floats.
// __launch_bounds__(1024,4): 4 waves/SIMD, VGPR cap 128 (no spill:
// max live ~ 64 w + 16 acc + addr).
// ---------------------------------------------------------------------------

__global__ __launch_bounds__(1024, 4) void actor_fused_kernel(
    const float* __restrict__ gs,
    const float* __restrict__ ls,
    const float* __restrict__ W_w, const float* __restrict__ W_b,
    const float* __restrict__ U_w, const float* __restrict__ U_b,
    const float* __restrict__ att_w, const float* __restrict__ att_b,
    const float* __restrict__ l1_w, const float* __restrict__ l1_b,
    const float* __restrict__ l2_w, const float* __restrict__ l2_b,
    const float* __restrict__ l3_w, const float* __restrict__ l3_b,
    float* __restrict__ out)
{
    __shared__ float c_lds[64];
    __shared__ __align__(16) float y_lds[ROWS][64];
    __shared__ __align__(16) float s_x [ROWS * 64];
    __shared__ __align__(16) float s_a1[ROWS * 260];  // pad 260: 16B-aligned rows,
    __shared__ __align__(16) float s_a2[ROWS * 260];  // bank-spread

    const int tid  = threadIdx.x;
    const int lane = tid & 63;
    const int wid  = tid >> 6;          // 0..15: row within block
    const int b    = blockIdx.x * ROWS + wid;

    const int h    = lane & 31;   // owned hidden unit (both halves)
    const int half = lane >> 5;   // d-half for 64-d dots
    const int q    = lane & 15;   // d-quad within l-group

    // ================= Phase A: attention pooling (per wave) =================
    // (per-wave logic byte-identical to R3's best-measured version)

    const float4* g4 = (const float4*)(gs + (size_t)b * 64);
    const float4* W4 = (const float4*)(W_w);
    float wg = (half == 0) ? W_b[h] : 0.f;
    #pragma unroll
    for (int dd = 0; dd < 8; ++dd) {
        float4 gv = g4[half * 8 + dd];
        float4 wv = W4[h * 16 + half * 8 + dd];
        wg += gv.x * wv.x + gv.y * wv.y + gv.z * wv.z + gv.w * wv.w;
    }
    wg += __shfl_xor(wg, 32);     // all lanes now hold wg[h]

    float gt = wg * att_w[h];
    float t2 = wg * att_w[HH + h];
    #pragma unroll
    for (int m = 1; m < 32; m <<= 1) {
        gt += __shfl_xor(gt, m);
        t2 += __shfl_xor(t2, m);
    }
    const float attb = att_b[0];
    const float lin0 = gt + t2 + attb;
    const float s0   = (lin0 > 0.f) ? lin0 : 0.01f * lin0;

    // ---- c[d] = sum_h a_l[h]*U_w[h][d]  (b-independent; benign race) ----
    float c = 0.f;
    float ubal = 0.f;
    #pragma unroll
    for (int hh = 0; hh < HH; ++hh) {
        const float alh = att_w[HH + hh];        // uniform -> s_load
        c    += alh * U_w[hh * 64 + lane];       // coalesced, L1-hot
        ubal += alh * U_b[hh];
    }
    c_lds[lane] = c;              // all 16 waves write identical values
    __syncthreads();
    const float4 cq = *(const float4*)&c_lds[4 * q];
    const float base = gt + ubal + attb;

    // ---- stream: 50 chunks x 1 KB, depth-PF VGPR ring (R3 exact) ----
    const float4* xs = (const float4*)(ls + (size_t)b * (LL * 64));
    float4 yx = make_float4(0.f, 0.f, 0.f, 0.f);
    float Sacc = 0.f;

    float4 Xbuf[PF];
    #pragma unroll
    for (int i = 0; i < PF; ++i)
        Xbuf[i] = xs[lane + i * 64];

    #pragma unroll                 // FULL unroll: ring index compile-time
    for (int t = 0; t < 50; ++t) {
        float4 X = Xbuf[t & (PF - 1)];
        int tn = t + PF;
        if (tn > 49) tn = 49;      // clamped redundant tail (L1-hot)
        Xbuf[t & (PF - 1)] = xs[lane + tn * 64];

        float p = X.x * cq.x + X.y * cq.y + X.z * cq.z + X.w * cq.w;
        p += __shfl_xor(p, 1);
        p += __shfl_xor(p, 2);
        p += __shfl_xor(p, 4);
        p += __shfl_xor(p, 8);     // 16-lane group dot: x[l].c
        const float linv = p + base;
        const float sl = (linv > 0.f) ? linv : 0.01f * linv;
        yx.x += sl * X.x;
        yx.y += sl * X.y;
        yx.z += sl * X.z;
        yx.w += sl * X.w;
        Sacc += sl;                // identical across the 16-lane group
    }

    #pragma unroll
    for (int m = 16; m < 64; m <<= 1) {
        yx.x += __shfl_xor(yx.x, m);
        yx.y += __shfl_xor(yx.y, m);
        yx.z += __shfl_xor(yx.z, m);
        yx.w += __shfl_xor(yx.w, m);
        Sacc += __shfl_xor(Sacc, m);
    }
    if (lane < 16) *(float4*)&y_lds[wid][4 * q] = yx;
    __syncthreads();

    // ---- V[h] = U_w[h].y + U_b[h]*S ----
    float V = (half == 0) ? (U_b[h] * Sacc) : 0.f;
    const float4* U4 = (const float4*)U_w;
    const float4* y4 = (const float4*)&y_lds[wid][0];
    #pragma unroll
    for (int dd = 0; dd < 8; ++dd) {
        float4 uv = U4[h * 16 + half * 8 + dd];
        float4 yv = y4[half * 8 + dd];
        V += uv.x * yv.x + uv.y * yv.y + uv.z * yv.z + uv.w * yv.w;
    }
    V += __shfl_xor(V, 32);        // all lanes hold full V[h]

    const float total = s0 + Sacc;
    const float n0    = s0 / total;
    const float outv  = (lane < 32) ? (n0 * wg) : (V / total);
    s_x[wid * 64 + lane] = fmaxf(outv, 0.f);   // states -> LDS
    __syncthreads();

    // ============ Phase B: MLP 64->256->256->8, 16-row amortized =============
    const int u = tid & 255;       // owned output unit (threads 0..255)

    // ---- layer 1: w row (64 f) in VGPRs, applied to 16 rows ----
    if (tid < 256) {
        float4 wv[16];
        const float4* wr4 = (const float4*)(l1_w + u * 64);
        #pragma unroll
        for (int i = 0; i < 16; ++i) wv[i] = wr4[i];
        float acc[ROWS];
        const float bias = l1_b[u];
        #pragma unroll
        for (int r = 0; r < ROWS; ++r) acc[r] = bias;
        #pragma unroll
        for (int i = 0; i < 16; ++i) {
            const float4 w4v = wv[i];
            #pragma unroll
            for (int r = 0; r < ROWS; ++r) {
                const float4 xv = *(const float4*)&s_x[r * 64 + i * 4];  // broadcast
                acc[r] += w4v.x * xv.x + w4v.y * xv.y + w4v.z * xv.z + w4v.w * xv.w;
            }
        }
        #pragma unroll
        for (int r = 0; r < ROWS; ++r)
            s_a1[r * 260 + u] = fmaxf(acc[r], 0.f);
    }
    __syncthreads();

    // ---- layer 2: 4 k-chunks of 64, w chunk in VGPRs, 16 rows ----
    if (tid < 256) {
        float acc[ROWS];
        const float bias = l2_b[u];
        #pragma unroll
        for (int r = 0; r < ROWS; ++r) acc[r] = bias;
        for (int kc = 0; kc < 4; ++kc) {
            float4 wv[16];
            const float4* wr4 = (const float4*)(l2_w + (size_t)u * 256 + kc * 64);
            #pragma unroll
            for (int i = 0; i < 16; ++i) wv[i] = wr4[i];
            #pragma unroll
            for (int i = 0; i < 16; ++i) {
                const float4 w4v = wv[i];
                #pragma unroll
                for (int r = 0; r < ROWS; ++r) {
                    const float4 av = *(const float4*)&s_a1[r * 260 + kc * 64 + i * 4];
                    acc[r] += w4v.x * av.x + w4v.y * av.y + w4v.z * av.z + w4v.w * av.w;
                }
            }
        }
        #pragma unroll
        for (int r = 0; r < ROWS; ++r)
            s_a2[r * 260 + u] = fmaxf(acc[r], 0.f);
    }
    __syncthreads();

    // ---- layer 3 + sigmoid: threads 0..127 (16 rows x 8 units) ----
    if (tid < 128) {
        const int r = tid >> 3, o = tid & 7;
        float acc = l3_b[o];
        const float4* wr4 = (const float4*)(l3_w + o * 256);
        const float4* a4  = (const float4*)&s_a2[r * 260];
        #pragma unroll 8
        for (int k = 0; k < 64; ++k) {
            float4 av = a4[k];
            float4 wvv = wr4[k];
            acc += av.x * wvv.x + av.y * wvv.y + av.z * wvv.z + av.w * wvv.w;
        }
        out[((size_t)blockIdx.x * ROWS + r) * 8 + o] =
            1.f / (1.f + __expf(-acc));   // MAX_ACTION = 1
    }
}

// ---------------------------------------------------------------------------
extern "C" void kernel_launch(void* const* d_in, const int* in_sizes, int n_in,
                              void* d_out, int out_size, void* d_ws, size_t ws_size,
                              hipStream_t stream)
{
    const float* gs    = (const float*)d_in[0];
    const float* ls    = (const float*)d_in[1];
    const float* W_w   = (const float*)d_in[2];
    const float* W_b   = (const float*)d_in[3];
    const float* U_w   = (const float*)d_in[4];
    const float* U_b   = (const float*)d_in[5];
    const float* att_w = (const float*)d_in[6];
    const float* att_b = (const float*)d_in[7];
    const float* l1_w  = (const float*)d_in[8];
    const float* l1_b  = (const float*)d_in[9];
    const float* l2_w  = (const float*)d_in[10];
    const float* l2_b  = (const float*)d_in[11];
    const float* l3_w  = (const float*)d_in[12];
    const float* l3_b  = (const float*)d_in[13];

    actor_fused_kernel<<<BB / ROWS, ROWS * 64, 0, stream>>>(
        gs, ls, W_w, W_b, U_w, U_b, att_w, att_b,
        l1_w, l1_b, l2_w, l2_b, l3_w, l3_b, (float*)d_out);
}

// Round 5
// 355.143 us; speedup vs baseline: 1.2640x; 1.1295x over previous
//
#include <hip/hip_runtime.h>
#include <math.h>

#define BB 4096
#define LL 200
#define HH 32
#define PF 8      // prefetch depth (outstanding global loads per wave)

// ---------------------------------------------------------------------------
// R8: byte-exact R3 (best measured: 143.5 us) with ONE change: the four
// inner-loop __shfl_xor(p,1/2/4/8) are replaced by DPP row_ror rotate-adds.
//
// Cross-round invariant (R3/R4/R5/R7): the stream held ~1.5 TB/s across
// VGPR-ring/scratch/LDS-DMA paths and 8->24.6 waves/CU occupancy, while
// the harness fill kernel hit 6.7 TB/s. The one unchanged hot-loop
// component: 4 DEPENDENT __shfl_xor per iteration = ds_bpermute chains on
// the LDS pipe (invisible to VALUBusy and to SQ_LDS_BANK_CONFLICT; counted
// only in lgkmcnt waits). 820K such chain-ops per dispatch. R6 corroborates:
// its phase-B added MORE shfl chains and cost +83 us.
//
// Fix: rotate-reduce within each 16-lane group via v_mov_b32_dpp
// row_ror:1/2/4/8 + v_add_f32 (VALU pipe, 1-2 cyc, no LDS crossbar).
// After ror:1,2,4,8 every lane holds the full 16-lane sum (same result
// as the xor butterfly). Out-of-loop shuffles (once per row) unchanged.
// ---------------------------------------------------------------------------

template<int CTRL>
__device__ __forceinline__ float dpp_ror_add(float x)
{
    // dst = x + rotate_within_row16(x, CTRL); VALU-pipe only.
    int y = __builtin_amdgcn_update_dpp(0, __float_as_int(x),
                                        CTRL, 0xF, 0xF, true);
    return x + __int_as_float(y);
}

__global__ __launch_bounds__(256) void actor_fused_kernel(
    const float* __restrict__ gs,
    const float* __restrict__ ls,
    const float* __restrict__ W_w, const float* __restrict__ W_b,
    const float* __restrict__ U_w, const float* __restrict__ U_b,
    const float* __restrict__ att_w, const float* __restrict__ att_b,
    const float* __restrict__ l1_w, const float* __restrict__ l1_b,
    const float* __restrict__ l2_w, const float* __restrict__ l2_b,
    const float* __restrict__ l3_w, const float* __restrict__ l3_b,
    float* __restrict__ out)
{
    __shared__ float c_lds[4 * 64];
    __shared__ float y_lds[4 * 64];
    __shared__ __align__(16) float s_x [4 * 64];
    __shared__ __align__(16) float s_a1[4 * 256];
    __shared__ __align__(16) float s_a2[4 * 260];  // pad 260: float4-able, conflict-free

    const int tid  = threadIdx.x;
    const int lane = tid & 63;
    const int wid  = tid >> 6;
    const int b    = blockIdx.x * 4 + wid;

    const int h    = lane & 31;   // owned hidden unit (both halves)
    const int half = lane >> 5;   // d-half for 64-d dots
    const int q    = lane & 15;   // d-quad within l-group
    const int lg   = lane >> 4;   // l-group 0..3

    // ================= Phase A: attention pooling (per wave) =================

    // ---- wg[h] = gs[b].W_w[h] + W_b[h]; halves split d, xor32 combine ----
    const float4* g4 = (const float4*)(gs + (size_t)b * 64);
    const float4* W4 = (const float4*)(W_w);
    float wg = (half == 0) ? W_b[h] : 0.f;
    #pragma unroll
    for (int dd = 0; dd < 8; ++dd) {
        float4 gv = g4[half * 8 + dd];
        float4 wv = W4[h * 16 + half * 8 + dd];
        wg += gv.x * wv.x + gv.y * wv.y + gv.z * wv.z + gv.w * wv.w;
    }
    wg += __shfl_xor(wg, 32);     // all lanes now hold wg[h]

    // ---- gt = wg.a_g ; t2 = wg.a_l (butterfly over h within 32-halves) ----
    float gt = wg * att_w[h];
    float t2 = wg * att_w[HH + h];
    #pragma unroll
    for (int m = 1; m < 32; m <<= 1) {
        gt += __shfl_xor(gt, m);
        t2 += __shfl_xor(t2, m);
    }
    const float attb = att_b[0];
    const float lin0 = gt + t2 + attb;
    const float s0   = (lin0 > 0.f) ? lin0 : 0.01f * lin0;

    // ---- c[d] = sum_h a_l[h]*U_w[h][d]  (lane owns d=lane) ----
    float c = 0.f;
    float ubal = 0.f;
    #pragma unroll
    for (int hh = 0; hh < HH; ++hh) {
        const float alh = att_w[HH + hh];        // uniform -> s_load
        c    += alh * U_w[hh * 64 + lane];       // coalesced, L1-hot
        ubal += alh * U_b[hh];
    }
    c_lds[wid * 64 + lane] = c;
    __syncthreads();
    const float4 cq = *(const float4*)&c_lds[wid * 64 + 4 * q];
    const float base = gt + ubal + attb;

    // ---- main stream: 50 chunks x 4 rows, depth-PF ring prefetch ----
    const float4* xs = (const float4*)(ls + (size_t)b * (LL * 64));
    const int idx0 = lg * 16 + q;
    float4 yx = make_float4(0.f, 0.f, 0.f, 0.f);
    float Sacc = 0.f;

    float4 Xbuf[PF];
    #pragma unroll
    for (int i = 0; i < PF; ++i)
        Xbuf[i] = xs[idx0 + i * 64];

    #pragma unroll                 // FULL unroll: ring index compile-time,
    for (int t = 0; t < 50; ++t) { // buffer lives in VGPRs, vmcnt waits
        float4 X = Xbuf[t & (PF - 1)];
        int tn = t + PF;
        if (tn > 49) tn = 49;      // clamped redundant tail (L1-hot)
        Xbuf[t & (PF - 1)] = xs[idx0 + tn * 64];

        float p = X.x * cq.x + X.y * cq.y + X.z * cq.z + X.w * cq.w;
        p = dpp_ror_add<0x121>(p);   // row_ror:1  } VALU-pipe 16-lane
        p = dpp_ror_add<0x122>(p);   // row_ror:2  } rotate-reduction:
        p = dpp_ror_add<0x124>(p);   // row_ror:4  } all lanes hold the
        p = dpp_ror_add<0x128>(p);   // row_ror:8  } group dot x[l].c
        const float linv = p + base;
        const float sl = (linv > 0.f) ? linv : 0.01f * linv;
        yx.x += sl * X.x;
        yx.y += sl * X.y;
        yx.z += sl * X.z;
        yx.w += sl * X.w;
        Sacc += sl;                // identical across the 16-lane group
    }

    // ---- combine the 4 l-groups (once per row, stays shfl) ----
    #pragma unroll
    for (int m = 16; m < 64; m <<= 1) {
        yx.x += __shfl_xor(yx.x, m);
        yx.y += __shfl_xor(yx.y, m);
        yx.z += __shfl_xor(yx.z, m);
        yx.w += __shfl_xor(yx.w, m);
        Sacc += __shfl_xor(Sacc, m);
    }
    if (lane < 16) *(float4*)&y_lds[wid * 64 + 4 * q] = yx;
    __syncthreads();

    // ---- V[h] = U_w[h].y + U_b[h]*S ----
    float V = (half == 0) ? (U_b[h] * Sacc) : 0.f;
    const float4* U4 = (const float4*)U_w;
    const float4* y4 = (const float4*)&y_lds[wid * 64];
    #pragma unroll
    for (int dd = 0; dd < 8; ++dd) {
        float4 uv = U4[h * 16 + half * 8 + dd];
        float4 yv = y4[half * 8 + dd];
        V += uv.x * yv.x + uv.y * yv.y + uv.z * yv.z + uv.w * yv.w;
    }
    V += __shfl_xor(V, 32);        // all lanes hold full V[h]

    const float total = s0 + Sacc;
    const float n0    = s0 / total;
    const float outv  = (lane < 32) ? (n0 * wg) : (V / total);
    s_x[wid * 64 + lane] = fmaxf(outv, 0.f);   // states -> LDS
    __syncthreads();

    // ================= Phase B: MLP 64->256->256->8 (block-wide) =============
    // (byte-identical to R3's measured version; optimize only after the
    //  stream A/B lands)

    float w[64];

    // ---- layer 1: thread owns unit tid; weight row in VGPRs ----
    {
        const float* wr = l1_w + tid * 64;
        #pragma unroll
        for (int d = 0; d < 64; ++d) w[d] = wr[d];
        float bias = l1_b[tid];
        #pragma unroll
        for (int r = 0; r < 4; ++r) {
            float acc = bias;
            #pragma unroll
            for (int d = 0; d < 64; ++d)
                acc += s_x[r * 64 + d] * w[d];   // LDS broadcast
            s_a1[r * 256 + tid] = fmaxf(acc, 0.f);
        }
    }
    __syncthreads();

    // ---- layer 2 ----
    {
        float acc[4];
        float bias = l2_b[tid];
        #pragma unroll
        for (int r = 0; r < 4; ++r) acc[r] = bias;
        for (int kc = 0; kc < 4; ++kc) {
            const float* wr = l2_w + tid * 256 + kc * 64;
            #pragma unroll
            for (int d = 0; d < 64; ++d) w[d] = wr[d];
            #pragma unroll
            for (int r = 0; r < 4; ++r) {
                #pragma unroll
                for (int d = 0; d < 64; ++d)
                    acc[r] += s_a1[r * 256 + kc * 64 + d] * w[d];
            }
        }
        #pragma unroll
        for (int r = 0; r < 4; ++r)
            s_a2[r * 260 + tid] = fmaxf(acc[r], 0.f);
    }
    __syncthreads();

    // ---- layer 3 + sigmoid: threads 0..31, float4 LDS reads ----
    if (tid < 32) {
        int r = tid >> 3, o = tid & 7;
        float acc = l3_b[o];
        const float4* wr4 = (const float4*)(l3_w + o * 256);
        const float4* a4  = (const float4*)&s_a2[r * 260];
        #pragma unroll 8
        for (int k = 0; k < 64; ++k) {
            float4 av = a4[k];
            float4 wv = wr4[k];
            acc += av.x * wv.x + av.y * wv.y + av.z * wv.z + av.w * wv.w;
        }
        out[(size_t)(blockIdx.x * 4 + r) * 8 + o] =
            1.f / (1.f + __expf(-acc));   // MAX_ACTION = 1
    }
}

// ---------------------------------------------------------------------------
extern "C" void kernel_launch(void* const* d_in, const int* in_sizes, int n_in,
                              void* d_out, int out_size, void* d_ws, size_t ws_size,
                              hipStream_t stream)
{
    const float* gs    = (const float*)d_in[0];
    const float* ls    = (const float*)d_in[1];
    const float* W_w   = (const float*)d_in[2];
    const float* W_b   = (const float*)d_in[3];
    const float* U_w   = (const float*)d_in[4];
    const float* U_b   = (const float*)d_in[5];
    const float* att_w = (const float*)d_in[6];
    const float* att_b = (const float*)d_in[7];
    const float* l1_w  = (const float*)d_in[8];
    const float* l1_b  = (const float*)d_in[9];
    const float* l2_w  = (const float*)d_in[10];
    const float* l2_b  = (const float*)d_in[11];
    const float* l3_w  = (const float*)d_in[12];
    const float* l3_b  = (const float*)d_in[13];

    actor_fused_kernel<<<BB / 4, 256, 0, stream>>>(
        gs, ls, W_w, W_b, U_w, U_b, att_w, att_b,
        l1_w, l1_b, l2_w, l2_b, l3_w, l3_b, (float*)d_out);
}

// Round 6
// 352.887 us; speedup vs baseline: 1.2721x; 1.0064x over previous
//
#include <hip/hip_runtime.h>
#include <math.h>

#define BB 4096
#define LL 200
#define HH 32
#define PF 8      // prefetch depth (outstanding global loads per wave)

// ---------------------------------------------------------------------------
// R9: phase A byte-identical to R8 (best measured: 130 us dispatch).
// Phase B rewritten = R6's coalescing + R8's DPP, minus R6's mistakes.
//
// R8 post-mortem: DPP swap in the stream bought -13.5 us (shfl-chain
// theory confirmed as partial). Remaining split: phase A ~65 us
// (210 MB @ 3.3 TB/s), phase B ~65 us for a 675-MFLOP MLP (~4 us of
// VALU). Phase B's cost is the per-thread weight-row gather: each
// float4 load touches 64 cache lines (lanes stride 256 B) -> ~82K TA
// cycles/CU = 26% of the dispatch budget, serialized on the per-CU TA,
// invisible to VALUBusy/FETCH (weights cache-hot).
//
// Fix: wave owns 64 units; each iteration the 4 lane-groups (lgb) take 4
// CONSECUTIVE units, so one weight-load instruction covers 1 KB
// contiguous (l1) / 4x256B (l2) = 4-8 lines instead of 64. 16-lane
// reduction via dpp_ror_add (VALU pipe; R6 used ds_bpermute chains).
// Activations hoisted to statically-indexed VGPRs once per layer; LDS
// rows padded to 260 (R6's 524K bank conflicts fixed).
// ---------------------------------------------------------------------------

template<int CTRL>
__device__ __forceinline__ float dpp_ror_add(float x)
{
    // dst = x + rotate_within_row16(x, CTRL); VALU-pipe only.
    int y = __builtin_amdgcn_update_dpp(0, __float_as_int(x),
                                        CTRL, 0xF, 0xF, true);
    return x + __int_as_float(y);
}

__global__ __launch_bounds__(256) void actor_fused_kernel(
    const float* __restrict__ gs,
    const float* __restrict__ ls,
    const float* __restrict__ W_w, const float* __restrict__ W_b,
    const float* __restrict__ U_w, const float* __restrict__ U_b,
    const float* __restrict__ att_w, const float* __restrict__ att_b,
    const float* __restrict__ l1_w, const float* __restrict__ l1_b,
    const float* __restrict__ l2_w, const float* __restrict__ l2_b,
    const float* __restrict__ l3_w, const float* __restrict__ l3_b,
    float* __restrict__ out)
{
    __shared__ float c_lds[4 * 64];
    __shared__ float y_lds[4 * 64];
    __shared__ __align__(16) float s_x [4 * 64];
    __shared__ __align__(16) float s_a1[4 * 260];  // pad 260: conflict-free
    __shared__ __align__(16) float s_a2[4 * 260];

    const int tid  = threadIdx.x;
    const int lane = tid & 63;
    const int wid  = tid >> 6;
    const int b    = blockIdx.x * 4 + wid;

    const int h    = lane & 31;   // owned hidden unit (both halves)
    const int half = lane >> 5;   // d-half for 64-d dots
    const int q    = lane & 15;   // d-quad within l-group
    const int lg   = lane >> 4;   // l-group 0..3

    // ================= Phase A: attention pooling (per wave) =================
    // (byte-identical to R8's measured version)

    const float4* g4 = (const float4*)(gs + (size_t)b * 64);
    const float4* W4 = (const float4*)(W_w);
    float wg = (half == 0) ? W_b[h] : 0.f;
    #pragma unroll
    for (int dd = 0; dd < 8; ++dd) {
        float4 gv = g4[half * 8 + dd];
        float4 wv = W4[h * 16 + half * 8 + dd];
        wg += gv.x * wv.x + gv.y * wv.y + gv.z * wv.z + gv.w * wv.w;
    }
    wg += __shfl_xor(wg, 32);     // all lanes now hold wg[h]

    float gt = wg * att_w[h];
    float t2 = wg * att_w[HH + h];
    #pragma unroll
    for (int m = 1; m < 32; m <<= 1) {
        gt += __shfl_xor(gt, m);
        t2 += __shfl_xor(t2, m);
    }
    const float attb = att_b[0];
    const float lin0 = gt + t2 + attb;
    const float s0   = (lin0 > 0.f) ? lin0 : 0.01f * lin0;

    float c = 0.f;
    float ubal = 0.f;
    #pragma unroll
    for (int hh = 0; hh < HH; ++hh) {
        const float alh = att_w[HH + hh];        // uniform -> s_load
        c    += alh * U_w[hh * 64 + lane];       // coalesced, L1-hot
        ubal += alh * U_b[hh];
    }
    c_lds[wid * 64 + lane] = c;
    __syncthreads();
    const float4 cq = *(const float4*)&c_lds[wid * 64 + 4 * q];
    const float base = gt + ubal + attb;

    const float4* xs = (const float4*)(ls + (size_t)b * (LL * 64));
    const int idx0 = lg * 16 + q;
    float4 yx = make_float4(0.f, 0.f, 0.f, 0.f);
    float Sacc = 0.f;

    float4 Xbuf[PF];
    #pragma unroll
    for (int i = 0; i < PF; ++i)
        Xbuf[i] = xs[idx0 + i * 64];

    #pragma unroll                 // FULL unroll: ring index compile-time,
    for (int t = 0; t < 50; ++t) { // buffer lives in VGPRs, vmcnt waits
        float4 X = Xbuf[t & (PF - 1)];
        int tn = t + PF;
        if (tn > 49) tn = 49;      // clamped redundant tail (L1-hot)
        Xbuf[t & (PF - 1)] = xs[idx0 + tn * 64];

        float p = X.x * cq.x + X.y * cq.y + X.z * cq.z + X.w * cq.w;
        p = dpp_ror_add<0x121>(p);   // row_ror:1  } VALU-pipe 16-lane
        p = dpp_ror_add<0x122>(p);   // row_ror:2  } rotate-reduction:
        p = dpp_ror_add<0x124>(p);   // row_ror:4  } all lanes hold the
        p = dpp_ror_add<0x128>(p);   // row_ror:8  } group dot x[l].c
        const float linv = p + base;
        const float sl = (linv > 0.f) ? linv : 0.01f * linv;
        yx.x += sl * X.x;
        yx.y += sl * X.y;
        yx.z += sl * X.z;
        yx.w += sl * X.w;
        Sacc += sl;                // identical across the 16-lane group
    }

    #pragma unroll
    for (int m = 16; m < 64; m <<= 1) {
        yx.x += __shfl_xor(yx.x, m);
        yx.y += __shfl_xor(yx.y, m);
        yx.z += __shfl_xor(yx.z, m);
        yx.w += __shfl_xor(yx.w, m);
        Sacc += __shfl_xor(Sacc, m);
    }
    if (lane < 16) *(float4*)&y_lds[wid * 64 + 4 * q] = yx;
    __syncthreads();

    float V = (half == 0) ? (U_b[h] * Sacc) : 0.f;
    const float4* U4 = (const float4*)U_w;
    const float4* y4 = (const float4*)&y_lds[wid * 64];
    #pragma unroll
    for (int dd = 0; dd < 8; ++dd) {
        float4 uv = U4[h * 16 + half * 8 + dd];
        float4 yv = y4[half * 8 + dd];
        V += uv.x * yv.x + uv.y * yv.y + uv.z * yv.z + uv.w * yv.w;
    }
    V += __shfl_xor(V, 32);        // all lanes hold full V[h]

    const float total = s0 + Sacc;
    const float n0    = s0 / total;
    const float outv  = (lane < 32) ? (n0 * wg) : (V / total);
    s_x[wid * 64 + lane] = fmaxf(outv, 0.f);   // states -> LDS
    __syncthreads();

    // ========= Phase B: MLP 64->256->256->8 (coalesced + DPP-reduced) ========
    // Wave wid owns units [wid*64, wid*64+64). Lane layout:
    //   lgb = lane>>4 : which of 4 CONSECUTIVE units this group handles
    //   kl  = lane&15 : k-slice (16 lanes x float4 cover 64 k's)
    const int kl  = lane & 15;
    const int lgb = lane >> 4;

    // ---- layer 1: 16 iters x 4 units; weight load = 1 KB contiguous ----
    {
        float4 xr[4];
        #pragma unroll
        for (int r = 0; r < 4; ++r)
            xr[r] = *(const float4*)&s_x[r * 64 + kl * 4];

        #pragma unroll
        for (int i = 0; i < 16; ++i) {
            const int u = (wid << 6) + (i << 2) + lgb;
            const float4 wv = *(const float4*)(l1_w + u * 64 + kl * 4);
            const float bias = l1_b[u];
            #pragma unroll
            for (int r = 0; r < 4; ++r) {
                float acc = wv.x * xr[r].x + wv.y * xr[r].y
                          + wv.z * xr[r].z + wv.w * xr[r].w;
                acc = dpp_ror_add<0x121>(acc);
                acc = dpp_ror_add<0x122>(acc);
                acc = dpp_ror_add<0x124>(acc);
                acc = dpp_ror_add<0x128>(acc);   // 16-lane sum, all lanes
                if (kl == 0)
                    s_a1[r * 260 + u] = fmaxf(acc + bias, 0.f);
            }
        }
    }
    __syncthreads();

    // ---- layer 2: a1 hoisted to 16 static float4 regs; 4x256B loads ----
    {
        float4 a1r[4][4];
        #pragma unroll
        for (int r = 0; r < 4; ++r)
            #pragma unroll
            for (int s = 0; s < 4; ++s)
                a1r[r][s] = *(const float4*)&s_a1[r * 260 + s * 64 + kl * 4];

        #pragma unroll
        for (int i = 0; i < 16; ++i) {
            const int u = (wid << 6) + (i << 2) + lgb;
            const float* wr = l2_w + (size_t)u * 256;
            const float4 wv0 = *(const float4*)(wr +   0 + kl * 4);
            const float4 wv1 = *(const float4*)(wr +  64 + kl * 4);
            const float4 wv2 = *(const float4*)(wr + 128 + kl * 4);
            const float4 wv3 = *(const float4*)(wr + 192 + kl * 4);
            const float bias = l2_b[u];
            #pragma unroll
            for (int r = 0; r < 4; ++r) {
                float acc = wv0.x * a1r[r][0].x + wv0.y * a1r[r][0].y
                          + wv0.z * a1r[r][0].z + wv0.w * a1r[r][0].w;
                acc      += wv1.x * a1r[r][1].x + wv1.y * a1r[r][1].y
                          + wv1.z * a1r[r][1].z + wv1.w * a1r[r][1].w;
                acc      += wv2.x * a1r[r][2].x + wv2.y * a1r[r][2].y
                          + wv2.z * a1r[r][2].z + wv2.w * a1r[r][2].w;
                acc      += wv3.x * a1r[r][3].x + wv3.y * a1r[r][3].y
                          + wv3.z * a1r[r][3].z + wv3.w * a1r[r][3].w;
                acc = dpp_ror_add<0x121>(acc);
                acc = dpp_ror_add<0x122>(acc);
                acc = dpp_ror_add<0x124>(acc);
                acc = dpp_ror_add<0x128>(acc);   // 16-lane sum, all lanes
                if (kl == 0)
                    s_a2[r * 260 + u] = fmaxf(acc + bias, 0.f);
            }
        }
    }
    __syncthreads();

    // ---- layer 3 + sigmoid: threads 0..31, float4 LDS reads (tiny) ----
    if (tid < 32) {
        int r = tid >> 3, o = tid & 7;
        float acc = l3_b[o];
        const float4* wr4 = (const float4*)(l3_w + o * 256);
        const float4* a4  = (const float4*)&s_a2[r * 260];
        #pragma unroll 8
        for (int k = 0; k < 64; ++k) {
            float4 av = a4[k];
            float4 wv = wr4[k];
            acc += av.x * wv.x + av.y * wv.y + av.z * wv.z + av.w * wv.w;
        }
        out[(size_t)(blockIdx.x * 4 + r) * 8 + o] =
            1.f / (1.f + __expf(-acc));   // MAX_ACTION = 1
    }
}

// ---------------------------------------------------------------------------
extern "C" void kernel_launch(void* const* d_in, const int* in_sizes, int n_in,
                              void* d_out, int out_size, void* d_ws, size_t ws_size,
                              hipStream_t stream)
{
    const float* gs    = (const float*)d_in[0];
    const float* ls    = (const float*)d_in[1];
    const float* W_w   = (const float*)d_in[2];
    const float* W_b   = (const float*)d_in[3];
    const float* U_w   = (const float*)d_in[4];
    const float* U_b   = (const float*)d_in[5];
    const float* att_w = (const float*)d_in[6];
    const float* att_b = (const float*)d_in[7];
    const float* l1_w  = (const float*)d_in[8];
    const float* l1_b  = (const float*)d_in[9];
    const float* l2_w  = (const float*)d_in[10];
    const float* l2_b  = (const float*)d_in[11];
    const float* l3_w  = (const float*)d_in[12];
    const float* l3_b  = (const float*)d_in[13];

    actor_fused_kernel<<<BB / 4, 256, 0, stream>>>(
        gs, ls, W_w, W_b, U_w, U_b, att_w, att_b,
        l1_w, l1_b, l2_w, l2_b, l3_w, l3_b, (float*)d_out);
}

// Round 7
// 340.038 us; speedup vs baseline: 1.3201x; 1.0378x over previous
//
#include <hip/hip_runtime.h>
#include <math.h>

#define BB 4096
#define LL 200
#define HH 32
#define PF 5      // prefetch ring depth (25 chunks % 5 == 0)

// ---------------------------------------------------------------------------
// R10: clean high-concurrency test. 512-thr blocks, 8 waves, 2 waves/row
// (25 chunks each, PF=5 ring), target VGPR<=64 -> 8 waves/SIMD ->
// 32 waves/CU (2x R9) with 2x per-row loads in flight.
//
// R9 post-mortem: phase-B rewrite moved -3 us => phase B ~10-20 us, NOT
// the 65 us I claimed; phase A ~110 us at 1.9 TB/s is the wall. Little's
// law says 16 waves/CU x 8 KB in flight should sustain >>6 TB/s, so
// effective outstanding depth must be ~1 -- OR concurrency helps and was
// never tested cleanly: R4 (the one high-occupancy run) was voided by
// scratch spill (launch_bounds cap ~256/w: (128,8)->32 regs, (1024,4)->64).
// This round: (512,4) -> cap 64, code kept lean to fit. Spill alarm =
// WRITE_SIZE. Phase B = R9's coalesced+DPP form over 8 waves x 32 units,
// layer-2 activations from LDS (broadcast, conflict-free) to save regs.
// ---------------------------------------------------------------------------

template<int CTRL>
__device__ __forceinline__ float dpp_ror_add(float x)
{
    // dst = x + rotate_within_row16(x, CTRL); VALU-pipe only.
    int y = __builtin_amdgcn_update_dpp(0, __float_as_int(x),
                                        CTRL, 0xF, 0xF, true);
    return x + __int_as_float(y);
}

__global__ __launch_bounds__(512, 4) void actor_fused_kernel(
    const float* __restrict__ gs,
    const float* __restrict__ ls,
    const float* __restrict__ W_w, const float* __restrict__ W_b,
    const float* __restrict__ U_w, const float* __restrict__ U_b,
    const float* __restrict__ att_w, const float* __restrict__ att_b,
    const float* __restrict__ l1_w, const float* __restrict__ l1_b,
    const float* __restrict__ l2_w, const float* __restrict__ l2_b,
    const float* __restrict__ l3_w, const float* __restrict__ l3_b,
    float* __restrict__ out)
{
    __shared__ float c_lds[64];
    __shared__ __align__(16) float y_part[8][64];
    __shared__ float S_part[8];
    __shared__ __align__(16) float s_x [4 * 64];
    __shared__ __align__(16) float s_a1[4 * 260];  // pad 260: conflict-free
    __shared__ __align__(16) float s_a2[4 * 260];

    const int tid  = threadIdx.x;
    const int lane = tid & 63;
    const int wid  = tid >> 6;          // 0..7
    const int rblk = wid >> 1;          // row within block 0..3
    const int hpart= wid & 1;           // which 100-l half of the row
    const int b    = blockIdx.x * 4 + rblk;

    const int h    = lane & 31;   // owned hidden unit (both halves)
    const int half = lane >> 5;   // d-half for 64-d dots
    const int q    = lane & 15;   // d-quad within l-group

    // ================= Phase A: attention pooling =================
    // (both waves of a pair compute identical wg/gt/s0 for their row)

    const float4* g4 = (const float4*)(gs + (size_t)b * 64);
    const float4* W4 = (const float4*)(W_w);
    float wg = (half == 0) ? W_b[h] : 0.f;
    #pragma unroll
    for (int dd = 0; dd < 8; ++dd) {
        float4 gv = g4[half * 8 + dd];
        float4 wv = W4[h * 16 + half * 8 + dd];
        wg += gv.x * wv.x + gv.y * wv.y + gv.z * wv.z + gv.w * wv.w;
    }
    wg += __shfl_xor(wg, 32);     // all lanes now hold wg[h]

    float gt = wg * att_w[h];
    float t2 = wg * att_w[HH + h];
    #pragma unroll
    for (int m = 1; m < 32; m <<= 1) {
        gt += __shfl_xor(gt, m);
        t2 += __shfl_xor(t2, m);
    }
    const float attb = att_b[0];
    const float lin0 = gt + t2 + attb;
    const float s0   = (lin0 > 0.f) ? lin0 : 0.01f * lin0;

    // ---- c[d] = sum_h a_l[h]*U_w[h][d] (b-independent; benign race) ----
    float c = 0.f;
    float ubal = 0.f;
    #pragma unroll
    for (int hh = 0; hh < HH; ++hh) {
        const float alh = att_w[HH + hh];        // uniform -> s_load
        c    += alh * U_w[hh * 64 + lane];       // coalesced, L1-hot
        ubal += alh * U_b[hh];
    }
    c_lds[lane] = c;              // all waves write identical values
    __syncthreads();
    const float4 cq = *(const float4*)&c_lds[4 * q];
    const float base = gt + ubal + attb;

    // ---- stream: this wave's 25 chunks (half a row), PF=5 ring ----
    const float4* xs = (const float4*)(ls + (size_t)b * (LL * 64));
    const int c0 = hpart * 25;
    float4 yx = make_float4(0.f, 0.f, 0.f, 0.f);
    float Sacc = 0.f;

    float4 Xbuf[PF];
    #pragma unroll
    for (int i = 0; i < PF; ++i)
        Xbuf[i] = xs[(c0 + i) * 64 + lane];

    #pragma unroll                 // FULL unroll: ring index compile-time
    for (int t = 0; t < 25; ++t) {
        float4 X = Xbuf[t % PF];
        if (t < 25 - PF)           // compile-time guard: clean tail
            Xbuf[t % PF] = xs[(c0 + t + PF) * 64 + lane];

        float p = X.x * cq.x + X.y * cq.y + X.z * cq.z + X.w * cq.w;
        p = dpp_ror_add<0x121>(p);   // row_ror:1  } VALU-pipe 16-lane
        p = dpp_ror_add<0x122>(p);   // row_ror:2  } rotate-reduction
        p = dpp_ror_add<0x124>(p);   // row_ror:4  }
        p = dpp_ror_add<0x128>(p);   // row_ror:8  } group dot x[l].c
        const float linv = p + base;
        const float sl = (linv > 0.f) ? linv : 0.01f * linv;
        yx.x += sl * X.x;
        yx.y += sl * X.y;
        yx.z += sl * X.z;
        yx.w += sl * X.w;
        Sacc += sl;                // identical across the 16-lane group
    }

    // ---- combine the 4 l-groups within the wave ----
    #pragma unroll
    for (int m = 16; m < 64; m <<= 1) {
        yx.x += __shfl_xor(yx.x, m);
        yx.y += __shfl_xor(yx.y, m);
        yx.z += __shfl_xor(yx.z, m);
        yx.w += __shfl_xor(yx.w, m);
        Sacc += __shfl_xor(Sacc, m);
    }
    if (lane < 16) *(float4*)&y_part[wid][4 * q] = yx;
    if (lane == 0) S_part[wid] = Sacc;
    __syncthreads();

    // ---- even wave of each pair finalizes its row ----
    if (!hpart) {
        const float Stot = S_part[wid] + S_part[wid + 1];
        float V = (half == 0) ? (U_b[h] * Stot) : 0.f;
        const float4* U4  = (const float4*)U_w;
        const float4* ya4 = (const float4*)&y_part[wid][0];
        const float4* yb4 = (const float4*)&y_part[wid + 1][0];
        #pragma unroll
        for (int dd = 0; dd < 8; ++dd) {
            float4 uv = U4[h * 16 + half * 8 + dd];
            float4 va = ya4[half * 8 + dd];     // broadcast within half
            float4 vb = yb4[half * 8 + dd];
            V += uv.x * (va.x + vb.x) + uv.y * (va.y + vb.y)
               + uv.z * (va.z + vb.z) + uv.w * (va.w + vb.w);
        }
        V += __shfl_xor(V, 32);    // all lanes hold full V[h]

        const float total = s0 + Stot;
        const float n0    = s0 / total;
        const float outv  = (lane < 32) ? (n0 * wg) : (V / total);
        s_x[rblk * 64 + lane] = fmaxf(outv, 0.f);
    }
    __syncthreads();

    // ===== Phase B: MLP 64->256->256->8 (8 waves x 32 units, coalesced) =====
    const int kl  = lane & 15;
    const int lgb = lane >> 4;

    // ---- layer 1: 8 iters x 4 consecutive units; 1 KB contiguous loads ----
    {
        float4 xr[4];
        #pragma unroll
        for (int r = 0; r < 4; ++r)
            xr[r] = *(const float4*)&s_x[r * 64 + kl * 4];

        #pragma unroll
        for (int i = 0; i < 8; ++i) {
            const int u = (wid << 5) + (i << 2) + lgb;
            const float4 wv = *(const float4*)(l1_w + u * 64 + kl * 4);
            const float bias = l1_b[u];
            #pragma unroll
            for (int r = 0; r < 4; ++r) {
                float acc = wv.x * xr[r].x + wv.y * xr[r].y
                          + wv.z * xr[r].z + wv.w * xr[r].w;
                acc = dpp_ror_add<0x121>(acc);
                acc = dpp_ror_add<0x122>(acc);
                acc = dpp_ror_add<0x124>(acc);
                acc = dpp_ror_add<0x128>(acc);   // 16-lane sum
                if (kl == 0)
                    s_a1[r * 260 + u] = fmaxf(acc + bias, 0.f);
            }
        }
    }
    __syncthreads();

    // ---- layer 2: weights 4x256B contiguous; a1 from LDS (broadcast) ----
    {
        #pragma unroll
        for (int i = 0; i < 8; ++i) {
            const int u = (wid << 5) + (i << 2) + lgb;
            const float* wr = l2_w + (size_t)u * 256;
            const float4 wv0 = *(const float4*)(wr +   0 + kl * 4);
            const float4 wv1 = *(const float4*)(wr +  64 + kl * 4);
            const float4 wv2 = *(const float4*)(wr + 128 + kl * 4);
            const float4 wv3 = *(const float4*)(wr + 192 + kl * 4);
            const float bias = l2_b[u];
            #pragma unroll
            for (int r = 0; r < 4; ++r) {
                const float4 a0 = *(const float4*)&s_a1[r * 260 +   0 + kl * 4];
                const float4 a1 = *(const float4*)&s_a1[r * 260 +  64 + kl * 4];
                const float4 a2 = *(const float4*)&s_a1[r * 260 + 128 + kl * 4];
                const float4 a3 = *(const float4*)&s_a1[r * 260 + 192 + kl * 4];
                float acc = wv0.x * a0.x + wv0.y * a0.y + wv0.z * a0.z + wv0.w * a0.w;
                acc      += wv1.x * a1.x + wv1.y * a1.y + wv1.z * a1.z + wv1.w * a1.w;
                acc      += wv2.x * a2.x + wv2.y * a2.y + wv2.z * a2.z + wv2.w * a2.w;
                acc      += wv3.x * a3.x + wv3.y * a3.y + wv3.z * a3.z + wv3.w * a3.w;
                acc = dpp_ror_add<0x121>(acc);
                acc = dpp_ror_add<0x122>(acc);
                acc = dpp_ror_add<0x124>(acc);
                acc = dpp_ror_add<0x128>(acc);   // 16-lane sum
                if (kl == 0)
                    s_a2[r * 260 + u] = fmaxf(acc + bias, 0.f);
            }
        }
    }
    __syncthreads();

    // ---- layer 3 + sigmoid: threads 0..31, float4 LDS reads (tiny) ----
    if (tid < 32) {
        int r = tid >> 3, o = tid & 7;
        float acc = l3_b[o];
        const float4* wr4 = (const float4*)(l3_w + o * 256);
        const float4* a4  = (const float4*)&s_a2[r * 260];
        #pragma unroll 8
        for (int k = 0; k < 64; ++k) {
            float4 av = a4[k];
            float4 wv = wr4[k];
            acc += av.x * wv.x + av.y * wv.y + av.z * wv.z + av.w * wv.w;
        }
        out[(size_t)(blockIdx.x * 4 + r) * 8 + o] =
            1.f / (1.f + __expf(-acc));   // MAX_ACTION = 1
    }
}

// ---------------------------------------------------------------------------
extern "C" void kernel_launch(void* const* d_in, const int* in_sizes, int n_in,
                              void* d_out, int out_size, void* d_ws, size_t ws_size,
                              hipStream_t stream)
{
    const float* gs    = (const float*)d_in[0];
    const float* ls    = (const float*)d_in[1];
    const float* W_w   = (const float*)d_in[2];
    const float* W_b   = (const float*)d_in[3];
    const float* U_w   = (const float*)d_in[4];
    const float* U_b   = (const float*)d_in[5];
    const float* att_w = (const float*)d_in[6];
    const float* att_b = (const float*)d_in[7];
    const float* l1_w  = (const float*)d_in[8];
    const float* l1_b  = (const float*)d_in[9];
    const float* l2_w  = (const float*)d_in[10];
    const float* l2_b  = (const float*)d_in[11];
    const float* l3_w  = (const float*)d_in[12];
    const float* l3_b  = (const float*)d_in[13];

    actor_fused_kernel<<<BB / 4, 512, 0, stream>>>(
        gs, ls, W_w, W_b, U_w, U_b, att_w, att_b,
        l1_w, l1_b, l2_w, l2_b, l3_w, l3_b, (float*)d_out);
}